// Round 13
// baseline (251.831 us; speedup 1.0000x reference)
//
#include <hip/hip_runtime.h>
#include <stdint.h>

constexpr int B = 2, C = 64, H = 192, W = 192;
constexpr int HW = H * W;
constexpr int P = B * H * W;          // 73728 pixels
constexpr float EPS = 1e-5f;

// XCD-aware bijective block swizzle (all grids divisible by 8). Chunks of ALL
// kernels cover the same contiguous pixel regions -> cross-kernel L2 reuse.
__device__ __forceinline__ int swz(int bid, int nwg) {
  return (bid & 7) * (nwg >> 3) + (bid >> 3);
}

// ---------------------------------------------------------------------------
// Kernel 1: NCHW -> NHWC transpose of x. Blocks 0..7 additionally transpose
// the weight tensors to channel-contiguous [tap][c] layouts (was k_prepw --
// merged to delete one launch + inter-kernel bubble; outputs independent).
// ---------------------------------------------------------------------------
__global__ __launch_bounds__(256) void k_transpose(const float* __restrict__ x,
    float* __restrict__ xt,
    const float* __restrict__ w1, const float* __restrict__ w2,
    const float* __restrict__ w3, const float* __restrict__ wdef,
    float* __restrict__ w1t, float* __restrict__ w2t,
    float* __restrict__ w3t, float* __restrict__ wdeft) {
  if (blockIdx.x < 8) {                       // prepw side-job
    int gid = blockIdx.x * 256 + threadIdx.x;
    const int stride = 8 * 256;
    for (int i = gid; i < 960; i += stride) { // [15][64]
      int c = i & 63, j = i >> 6;
      w1t[i] = w1[c * 15 + j];
      w2t[i] = w2[c * 15 + j];
    }
    for (int i = gid; i < 576; i += stride) { // [9][64]
      int c = i & 63, j = i >> 6;
      w3t[i] = w3[c * 9 + j];
    }
    for (int i = gid; i < 1728; i += stride) {// [27][64] (di*9+k major)
      int c = i & 63, jk = i >> 6;
      int di = jk / 9, k = jk % 9;
      wdeft[i] = wdef[di * (C * 9) + c * 9 + k];
    }
  }
  int blk = swz(blockIdx.x, B * H * (W / 64));
  int wt  = blk % (W / 64);
  int h   = (blk / (W / 64)) % H;
  int b   = blk / ((W / 64) * H);
  int w0  = wt * 64;
  __shared__ float tile[64][65];
  int tx = threadIdx.x & 63;
  int ty = threadIdx.x >> 6;
  #pragma unroll
  for (int c = ty; c < 64; c += 4)
    tile[c][tx] = x[((b * C + c) * H + h) * W + w0 + tx];
  __syncthreads();
  #pragma unroll
  for (int wi = ty; wi < 64; wi += 4)
    xt[((b * H + h) * W + w0 + wi) * 64 + tx] = tile[tx][wi];
}

// ---------------------------------------------------------------------------
// Kernel 2: FUSED off_sum + offsets (unchanged from r8, passed at absmax .03)
// ---------------------------------------------------------------------------
__global__ __launch_bounds__(256) void k_offpipe(const float* __restrict__ xt,
    const float* __restrict__ w1t, const float* __restrict__ b1, const float* __restrict__ bn1,
    const float* __restrict__ w2t, const float* __restrict__ b2, const float* __restrict__ bn2,
    const float* __restrict__ w3t, const float* __restrict__ b3, const float* __restrict__ bn3,
    const float* __restrict__ wq, const float* __restrict__ bq, const float* __restrict__ bnq,
    float* __restrict__ offs) {
  __shared__ float os[16][68];
  __shared__ float wqs[18][66];
  __shared__ float qsc[18], qsh[18];

  int blk = swz(blockIdx.x, P / 16);
  int w0t = (blk % (W / 16)) * 16;
  int h   = (blk / (W / 16)) % H;
  int b   = blk / ((W / 16) * H);
  int wl  = threadIdx.x >> 6;
  int c   = threadIdx.x & 63;
  int w0  = w0t + wl * 4;
  const float* xb = xt + (size_t)b * HW * 64 + c;

  for (int i = threadIdx.x; i < 18 * 64; i += 256)
    wqs[i >> 6][i & 63] = wq[i];
  if (threadIdx.x < 18) {
    int o = threadIdx.x;
    float sc = bnq[o] / sqrtf(bnq[54 + o] + EPS);
    qsc[o] = sc;
    qsh[o] = fmaf(bq[o], sc, bnq[18 + o] - bnq[36 + o] * sc);
  }

  float s1[4] = {0.f, 0.f, 0.f, 0.f};
  float s2[4] = {0.f, 0.f, 0.f, 0.f};
  float s3[4] = {0.f, 0.f, 0.f, 0.f};
  {
    float xv[18];
    #pragma unroll
    for (int j = 0; j < 18; ++j) {
      int ww = w0 - 7 + j;
      xv[j] = (ww >= 0 && ww < W) ? xb[(h * W + ww) * 64] : 0.f;
    }
    #pragma unroll
    for (int j = 0; j < 15; ++j) {
      float wj = w1t[j * 64 + c];
      #pragma unroll
      for (int p = 0; p < 4; ++p) s1[p] = fmaf(xv[p + j], wj, s1[p]);
    }
  }
  #pragma unroll
  for (int j = 0; j < 15; ++j) {
    int hh = h - 7 + j;
    if (hh >= 0 && hh < H) {
      float wj = w2t[j * 64 + c];
      #pragma unroll
      for (int p = 0; p < 4; ++p)
        s2[p] = fmaf(xb[(hh * W + w0 + p) * 64], wj, s2[p]);
    }
  }
  #pragma unroll
  for (int dy = -1; dy <= 1; ++dy) {
    int hh = h + dy;
    if (hh >= 0 && hh < H) {
      float rv[6];
      #pragma unroll
      for (int j = 0; j < 6; ++j) {
        int ww = w0 - 1 + j;
        rv[j] = (ww >= 0 && ww < W) ? xb[(hh * W + ww) * 64] : 0.f;
      }
      #pragma unroll
      for (int dx = 0; dx < 3; ++dx) {
        float wj = w3t[((dy + 1) * 3 + dx) * 64 + c];
        #pragma unroll
        for (int p = 0; p < 4; ++p) s3[p] = fmaf(rv[p + dx], wj, s3[p]);
      }
    }
  }
  float sc1 = bn1[c] / sqrtf(bn1[192 + c] + EPS);
  float sh1 = bn1[64 + c] - bn1[128 + c] * sc1;
  float sc2 = bn2[c] / sqrtf(bn2[192 + c] + EPS);
  float sh2 = bn2[64 + c] - bn2[128 + c] * sc2;
  float sc3 = bn3[c] / sqrtf(bn3[192 + c] + EPS);
  float sh3 = bn3[64 + c] - bn3[128 + c] * sc3;
  float bb1 = b1[c], bb2 = b2[c], bb3 = b3[c];
  #pragma unroll
  for (int p = 0; p < 4; ++p)
    os[wl * 4 + p][c] =
        fmaf(s1[p] + bb1, sc1, sh1) + fmaf(s2[p] + bb2, sc2, sh2) +
        fmaf(s3[p] + bb3, sc3, sh3);
  __syncthreads();

  int p  = threadIdx.x & 15;
  int og = threadIdx.x >> 4;
  float dreg[64];
  #pragma unroll
  for (int q = 0; q < 16; ++q) {
    float4 v = *(float4*)&os[p][q * 4];
    dreg[4 * q + 0] = v.x; dreg[4 * q + 1] = v.y;
    dreg[4 * q + 2] = v.z; dreg[4 * q + 3] = v.w;
  }
  size_t pix = (size_t)((b * H + h) * W + w0t + p);
  #pragma unroll
  for (int pass = 0; pass < 2; ++pass) {
    int o = (pass == 0) ? og : 16 + og;
    if (pass == 1 && og >= 2) break;
    float a0 = 0.f, a1 = 0.f, a2 = 0.f, a3 = 0.f;
    #pragma unroll
    for (int q = 0; q < 16; ++q) {
      float4 ww = *(float4*)&wqs[o][q * 4];
      a0 = fmaf(dreg[4 * q + 0], ww.x, a0);
      a1 = fmaf(dreg[4 * q + 1], ww.y, a1);
      a2 = fmaf(dreg[4 * q + 2], ww.z, a2);
      a3 = fmaf(dreg[4 * q + 3], ww.w, a3);
    }
    float s = (a0 + a1) + (a2 + a3);
    offs[pix * 18 + o] = fmaf(s, qsc[o], qsh[o]);
  }
}

// ---------------------------------------------------------------------------
// Kernel 4: FUSED precomp + deform_sum, ZERO LDS. One wave per pixel.
// Phase 1: all 64 lanes compute a tap (lanes 27+ duplicate; no divergence,
// no barrier). Phase 2: per tap, broadcast the 8 dwords via readlane
// (compile-time lane index -> SGPR, VALU pipe) instead of LDS (r8: 54
// uniform ds_read_b128/wave = ~78 us of shared-LDS-pipe serialization).
// Gathers: global_load v, v_c4, s[base]. Center tap gathered once (bit-
// identical across dilations), 3 FMAs with same bil: 108 -> 100 gathers.
// ---------------------------------------------------------------------------
__global__ __launch_bounds__(256) void k_deform(const float* __restrict__ xt,
                                                const float* __restrict__ offs,
                                                const float* __restrict__ wdeft,
                                                float* __restrict__ dsum) {
  int wl   = threadIdx.x >> 6;
  int lane = threadIdx.x & 63;
  int pix  = swz(blockIdx.x, P / 4) * 4 + wl;

  // ---- phase 1: per-tap coordinate precompute on all lanes ----
  int li = lane;
  if (li >= 54) li -= 54;
  if (li >= 27) li -= 27;
  int di = li / 9, k = li % 9;
  uint32_t o00, o01, o10, o11, bw00, bw01, bw10, bw11;
  {
    int d  = 1 << di;                       // 1,2,4
    int w = pix % W, h = (pix / W) % H;
    const float* op = offs + (size_t)pix * 18;
    float offy = op[2 * k];
    float offx = op[2 * k + 1];
    int ky = k / 3 - 1, kx = k % 3 - 1;
    float yy = (offy + (float)h) + (float)(ky * d);
    float xx = (offx + (float)w) + (float)(kx * d);
    float y0f = floorf(yy), x0f = floorf(xx);
    float wy1 = yy - y0f, wx1 = xx - x0f;
    float wy0 = 1.f - wy1, wx0 = 1.f - wx1;
    int y0 = (int)fmaxf(fminf(y0f, 1.0e4f), -1.0e4f);
    int x0 = (int)fmaxf(fminf(x0f, 1.0e4f), -1.0e4f);
    int y1 = y0 + 1, x1 = x0 + 1;
    float my0 = (y0 >= 0 && y0 < H) ? 1.f : 0.f;
    float my1 = (y1 >= 0 && y1 < H) ? 1.f : 0.f;
    float mx0 = (x0 >= 0 && x0 < W) ? 1.f : 0.f;
    float mx1 = (x1 >= 0 && x1 < W) ? 1.f : 0.f;
    int y0c = min(max(y0, 0), H - 1), y1c = min(max(y1, 0), H - 1);
    int x0c = min(max(x0, 0), W - 1), x1c = min(max(x1, 0), W - 1);
    int r0 = y0c * W, r1 = y1c * W;
    float wy0m = wy0 * my0, wy1m = wy1 * my1;
    float wx0m = wx0 * mx0, wx1m = wx1 * mx1;
    o00 = (uint32_t)(r0 + x0c) << 8;        // byte offsets (row*64ch*4B)
    o01 = (uint32_t)(r0 + x1c) << 8;
    o10 = (uint32_t)(r1 + x0c) << 8;
    o11 = (uint32_t)(r1 + x1c) << 8;
    bw00 = __float_as_uint(wy0m * wx0m);
    bw01 = __float_as_uint(wy0m * wx1m);
    bw10 = __float_as_uint(wy1m * wx0m);
    bw11 = __float_as_uint(wy1m * wx1m);
  }

  // ---- phase 2: gathers + accumulate (no barrier needed: same wave) ----
  int c = lane;
  int b = pix / HW;
  const char* xb0 = (const char*)(xt + (size_t)b * HW * 64);

  float wd[27];
  #pragma unroll
  for (int i = 0; i < 27; ++i) wd[i] = wdeft[i * 64 + c];   // coalesced

  float acc = 0.f;
  #pragma unroll
  for (int t = 0; t < 27; ++t) {
    if (t == 13 || t == 22) continue;       // folded into t==4 (identical)
    int s00 = __builtin_amdgcn_readlane((int)o00, t);
    int s01 = __builtin_amdgcn_readlane((int)o01, t);
    int s10 = __builtin_amdgcn_readlane((int)o10, t);
    int s11 = __builtin_amdgcn_readlane((int)o11, t);
    float w00 = __uint_as_float(__builtin_amdgcn_readlane((int)bw00, t));
    float w01 = __uint_as_float(__builtin_amdgcn_readlane((int)bw01, t));
    float w10 = __uint_as_float(__builtin_amdgcn_readlane((int)bw10, t));
    float w11 = __uint_as_float(__builtin_amdgcn_readlane((int)bw11, t));
    const float* p00 = (const float*)(xb0 + s00);
    const float* p01 = (const float*)(xb0 + s01);
    const float* p10 = (const float*)(xb0 + s10);
    const float* p11 = (const float*)(xb0 + s11);
    float v00 = p00[c], v01 = p01[c], v10 = p10[c], v11 = p11[c];
    float bil = fmaf(v11, w11, fmaf(v10, w10, fmaf(v01, w01, v00 * w00)));
    if (t == 4) {                           // center: same bil, 3 dil weights
      acc = fmaf(wd[4], bil, acc);
      acc = fmaf(wd[13], bil, acc);
      acc = fmaf(wd[22], bil, acc);
    } else {
      acc = fmaf(wd[t], bil, acc);
    }
  }
  dsum[(size_t)pix * 64 + c] = acc;
}

// ---------------------------------------------------------------------------
// Kernel 5: out = bn(1x1 conv 64->64) * x    (NHWC in, NCHW out)
// ---------------------------------------------------------------------------
__global__ __launch_bounds__(256) void k_final(const float* __restrict__ ds,
    const float* __restrict__ x, const float* __restrict__ wb,
    const float* __restrict__ bb, const float* __restrict__ bnb,
    float* __restrict__ out) {
  int blk = swz(blockIdx.x, P / 64);
  int w0 = (blk % (W / 64)) * 64;
  int h  = (blk / (W / 64)) % H;
  int b  = blk / ((W / 64) * H);
  __shared__ float dtile[64][68];
  __shared__ float scs[64], shb[64];
  int tx = threadIdx.x & 63;
  int ty = threadIdx.x >> 6;
  int pixbase = (b * H + h) * W + w0;

  {
    int pr  = threadIdx.x >> 4;
    int ic4 = (threadIdx.x & 15) * 4;
    #pragma unroll
    for (int pass = 0; pass < 4; ++pass) {
      int pix = pass * 16 + pr;
      float4 v = *(const float4*)&ds[(size_t)(pixbase + pix) * 64 + ic4];
      *(float4*)&dtile[pix][ic4] = v;
    }
  }
  if (threadIdx.x < 64) {
    float g = bnb[threadIdx.x], vv = bnb[192 + threadIdx.x];
    float sc = g / sqrtf(vv + EPS);
    scs[threadIdx.x] = sc;
    shb[threadIdx.x] = fmaf(bb[threadIdx.x], sc,
                            bnb[64 + threadIdx.x] - bnb[128 + threadIdx.x] * sc);
  }
  __syncthreads();

  float dreg[64];
  #pragma unroll
  for (int q = 0; q < 16; ++q) {
    float4 v = *(float4*)&dtile[tx][q * 4];
    dreg[4 * q + 0] = v.x; dreg[4 * q + 1] = v.y;
    dreg[4 * q + 2] = v.z; dreg[4 * q + 3] = v.w;
  }

  int ocb = __builtin_amdgcn_readfirstlane(ty);
  #pragma unroll
  for (int j = 0; j < 16; ++j) {
    int oc = ocb + 4 * j;
    const float* wr = wb + oc * 64;
    float a0 = 0.f, a1 = 0.f, a2 = 0.f, a3 = 0.f;
    #pragma unroll
    for (int q = 0; q < 16; ++q) {
      a0 = fmaf(dreg[4 * q + 0], wr[4 * q + 0], a0);
      a1 = fmaf(dreg[4 * q + 1], wr[4 * q + 1], a1);
      a2 = fmaf(dreg[4 * q + 2], wr[4 * q + 2], a2);
      a3 = fmaf(dreg[4 * q + 3], wr[4 * q + 3], a3);
    }
    float s = (a0 + a1) + (a2 + a3);
    float val = fmaf(s, scs[oc], shb[oc]);
    int xi = ((b * C + oc) * H + h) * W + w0 + tx;
    out[xi] = val * x[xi];
  }
}

// ---------------------------------------------------------------------------
extern "C" void kernel_launch(void* const* d_in, const int* in_sizes, int n_in,
                              void* d_out, int out_size, void* d_ws, size_t ws_size,
                              hipStream_t stream) {
  const float* x     = (const float*)d_in[0];
  const float* w1    = (const float*)d_in[1];
  const float* b1    = (const float*)d_in[2];
  const float* bn1   = (const float*)d_in[3];
  const float* w2    = (const float*)d_in[4];
  const float* b2    = (const float*)d_in[5];
  const float* bn2   = (const float*)d_in[6];
  const float* w3    = (const float*)d_in[7];
  const float* b3    = (const float*)d_in[8];
  const float* bn3   = (const float*)d_in[9];
  const float* wbo   = (const float*)d_in[10];
  const float* bbo   = (const float*)d_in[11];
  const float* bnbo  = (const float*)d_in[12];
  const float* wdef  = (const float*)d_in[13];
  const float* wbal  = (const float*)d_in[14];
  const float* bbal  = (const float*)d_in[15];
  const float* bnbal = (const float*)d_in[16];
  float* out = (float*)d_out;

  float* xt    = (float*)d_ws;                  // P*64 f
  float* dsum  = xt + (size_t)P * 64;           // P*64 f
  float* offs  = dsum + (size_t)P * 64;         // P*18 f
  float* wts   = offs + (size_t)P * 18;         // 4224 f
  float* w1t   = wts;                           // [15][64]
  float* w2t   = wts + 960;                     // [15][64]
  float* w3t   = wts + 1920;                    // [9][64]
  float* wdeft = wts + 2496;                    // [27][64]

  k_transpose<<<B * H * (W / 64), 256, 0, stream>>>(x, xt, w1, w2, w3, wdef,
                                                    w1t, w2t, w3t, wdeft);
  k_offpipe<<<P / 16, 256, 0, stream>>>(xt, w1t, b1, bn1, w2t, b2, bn2,
                                        w3t, b3, bn3, wbo, bbo, bnbo, offs);
  k_deform<<<P / 4, 256, 0, stream>>>(xt, offs, wdeft, dsum);
  k_final<<<P / 64, 256, 0, stream>>>(dsum, x, wbal, bbal, bnbal, out);
}